// Round 1
// 90627.307 us; speedup vs baseline: 1.7113x; 1.7113x over previous
//
#include <hip/hip_runtime.h>
#include <cstdint>
#include <cstddef>

typedef _Float16 h2v __attribute__((ext_vector_type(2)));
typedef _Float16 h8v __attribute__((ext_vector_type(8)));

#define NEG_SLOPE 0.2f
#define BN_EPS 1e-5f
#define BM 64
#define BN 64
#define BK 16
#define GCHUNK 1024   // GRU pipeline chunk (steps); must be multiple of 8

__device__ __forceinline__ float lrelu(float x) { return x > 0.f ? x : NEG_SLOPE * x; }

__device__ __forceinline__ unsigned fenc(float f) {
  unsigned b = __float_as_uint(f);
  return (b & 0x80000000u) ? ~b : (b | 0x80000000u);
}
__device__ __forceinline__ float fdec(unsigned u) {
  return (u & 0x80000000u) ? __uint_as_float(u & 0x7fffffffu) : __uint_as_float(~u);
}

__device__ __forceinline__ float fdot2f(h2v a, h2v b, float c) {
#if __has_builtin(__builtin_amdgcn_fdot2)
  return __builtin_amdgcn_fdot2(a, b, c, false);
#else
  return c + (float)a.x * (float)b.x + (float)a.y * (float)b.y;
#endif
}
__device__ __forceinline__ float sigf(float x) { return 1.f / (1.f + __expf(-x)); }
__device__ __forceinline__ float tanhfast(float x) {
  x = fminf(fmaxf(x, -20.f), 20.f);
  float e = __expf(2.f * x);
  return (e - 1.f) / (e + 1.f);
}

// ---------------- GAT layer 1 (rank-1 collapse) ----------------

__global__ __launch_bounds__(256) void k_prep_c(const float* __restrict__ W1,
                                                const float* __restrict__ as1,
                                                const float* __restrict__ ad1,
                                                float* __restrict__ c12) {
  __shared__ float r1[256], r2[256];
  int j = threadIdx.x;
  float wv = W1[j];
  r1[j] = wv * as1[j];
  r2[j] = wv * ad1[j];
  __syncthreads();
  for (int s = 128; s > 0; s >>= 1) {
    if (j < s) { r1[j] += r1[j + s]; r2[j] += r2[j + s]; }
    __syncthreads();
  }
  if (j == 0) { c12[0] = r1[0]; c12[1] = r2[0]; }
}

__global__ __launch_bounds__(256) void k_a1(const float* __restrict__ x, const float* __restrict__ c12,
                                            float* __restrict__ a1s, float* __restrict__ a1d, int N) {
  int i = blockIdx.x * 256 + threadIdx.x;
  if (i < N) {
    float xv = x[i];
    a1s[i] = c12[0] * xv;
    a1d[i] = c12[1] * xv;
  }
}

__global__ __launch_bounds__(256) void k_edge_max(const float* __restrict__ as_, const float* __restrict__ ad_,
                                                  unsigned* __restrict__ menc, const int* __restrict__ src,
                                                  const int* __restrict__ dst, int E, int N) {
  int i = blockIdx.x * 256 + threadIdx.x;
  if (i >= E + N) return;
  int s, d;
  if (i < E) { s = src[i]; d = dst[i]; } else { s = i - E; d = s; }
  float e = lrelu(as_[s] + ad_[d]);
  atomicMax(&menc[d], fenc(e));
}

__global__ __launch_bounds__(256) void k_gat1_edge_sum(const float* __restrict__ as_, const float* __restrict__ ad_,
                                                       const unsigned* __restrict__ menc, const int* __restrict__ src,
                                                       const int* __restrict__ dst, const float* __restrict__ x,
                                                       float* __restrict__ z, float* __restrict__ uacc, int E, int N) {
  int i = blockIdx.x * 256 + threadIdx.x;
  if (i >= E + N) return;
  int s, d;
  if (i < E) { s = src[i]; d = dst[i]; } else { s = i - E; d = s; }
  float e = lrelu(as_[s] + ad_[d]);
  float p = __expf(e - fdec(menc[d]));
  atomicAdd(&z[d], p);
  atomicAdd(&uacc[d], p * x[s]);
}

__global__ __launch_bounds__(256) void k_gat1_node(const float* __restrict__ uacc, const float* __restrict__ z1,
                                                   const float* __restrict__ W1, const float* __restrict__ b1,
                                                   const float* __restrict__ gamma, const float* __restrict__ beta,
                                                   const float* __restrict__ mean, const float* __restrict__ var,
                                                   float* __restrict__ h1) {
  int n = blockIdx.x, j = threadIdx.x;
  float u = uacc[n] / z1[n];
  float v = u * W1[j] + b1[j];
  v = (v - mean[j]) * rsqrtf(var[j] + BN_EPS) * gamma[j] + beta[j];
  h1[(size_t)n * 256 + j] = fmaxf(v, 0.f);
}

// ---------------- generic fp32 tiled GEMM: C[M,N] = A[M,K] * B[K,N] ----------------

__global__ __launch_bounds__(256) void k_gemm_f32(const float* __restrict__ A, const float* __restrict__ B,
                                                  float* __restrict__ C, int M, int N, int K) {
  __shared__ float As[BK][BM];
  __shared__ float Bs[BK][BN];
  int tid = threadIdx.x;
  int m0 = blockIdx.x * BM, n0 = blockIdx.y * BN;
  int lm = tid >> 2;
  int lk4 = (tid & 3) * 4;
  int bn_ = tid & 63;
  int bkq = (tid >> 6) * 4;
  int tm = (tid >> 4) * 4, tn = (tid & 15) * 4;
  float acc[4][4] = {};
  for (int k0 = 0; k0 < K; k0 += BK) {
    float4 av4 = make_float4(0.f, 0.f, 0.f, 0.f);
    if (m0 + lm < M) av4 = *(const float4*)(A + (size_t)(m0 + lm) * K + k0 + lk4);
    As[lk4 + 0][lm] = av4.x;
    As[lk4 + 1][lm] = av4.y;
    As[lk4 + 2][lm] = av4.z;
    As[lk4 + 3][lm] = av4.w;
#pragma unroll
    for (int c = 0; c < 4; ++c) {
      int k = k0 + bkq + c;
      Bs[bkq + c][bn_] = (k < K) ? B[(size_t)k * N + n0 + bn_] : 0.f;
    }
    __syncthreads();
#pragma unroll
    for (int kk = 0; kk < BK; ++kk) {
      float av[4], bv[4];
#pragma unroll
      for (int i = 0; i < 4; ++i) { av[i] = As[kk][tm + i]; bv[i] = Bs[kk][tn + i]; }
#pragma unroll
      for (int i = 0; i < 4; ++i)
#pragma unroll
        for (int jj = 0; jj < 4; ++jj) acc[i][jj] = fmaf(av[i], bv[jj], acc[i][jj]);
    }
    __syncthreads();
  }
#pragma unroll
  for (int i = 0; i < 4; ++i) {
    int m = m0 + tm + i;
    if (m < M) {
      float4 v = make_float4(acc[i][0], acc[i][1], acc[i][2], acc[i][3]);
      *(float4*)(C + (size_t)m * N + n0 + tn) = v;
    }
  }
}

// ---------------- row dots for GAT2 attention scalars ----------------

__global__ __launch_bounds__(256) void k_rowdots(const float* __restrict__ xw2, const float* __restrict__ as2,
                                                 const float* __restrict__ ad2, float* __restrict__ a2s,
                                                 float* __restrict__ a2d) {
  __shared__ float r1[256], r2[256];
  int n = blockIdx.x, j = threadIdx.x;
  float v = xw2[(size_t)n * 256 + j];
  r1[j] = v * as2[j];
  r2[j] = v * ad2[j];
  __syncthreads();
  for (int s = 128; s > 0; s >>= 1) {
    if (j < s) { r1[j] += r1[j + s]; r2[j] += r2[j + s]; }
    __syncthreads();
  }
  if (j == 0) { a2s[n] = r1[0]; a2d[n] = r2[0]; }
}

__global__ __launch_bounds__(256) void k_gat2_scatter(const float* __restrict__ a2s, const float* __restrict__ a2d,
                                                      const unsigned* __restrict__ m2, const int* __restrict__ src,
                                                      const int* __restrict__ dst, const float* __restrict__ xw2,
                                                      float* __restrict__ z2, float* __restrict__ acc2, int E, int N) {
  int j = threadIdx.x;
  for (int i = blockIdx.x; i < E + N; i += gridDim.x) {
    int s, d;
    if (i < E) { s = src[i]; d = dst[i]; } else { s = i - E; d = s; }
    float e = lrelu(a2s[s] + a2d[d]);
    float p = __expf(e - fdec(m2[d]));
    if (j == 0) atomicAdd(&z2[d], p);
    atomicAdd(&acc2[(size_t)d * 256 + j], p * xw2[(size_t)s * 256 + j]);
  }
}

__global__ __launch_bounds__(256) void k_gat2_node(float* __restrict__ acc2, const float* __restrict__ z2,
                                                   const float* __restrict__ b2, const float* __restrict__ gamma,
                                                   const float* __restrict__ beta, const float* __restrict__ mean,
                                                   const float* __restrict__ var) {
  int n = blockIdx.x, j = threadIdx.x;
  size_t idx = (size_t)n * 256 + j;
  float v = acc2[idx] / z2[n] + b2[j];
  v = (v - mean[j]) * rsqrtf(var[j] + BN_EPS) * gamma[j] + beta[j];
  acc2[idx] = fmaxf(v, 0.f);
}

// ---------------- gi0 GEMM: outT[Nout,M](f16) = (A[M,K] * W[Nout,K]^T + bias)^T ----------------
// mode 0 only now: A = gathered edge features [h2[src], h2[dst], ea]  (K=515)

__global__ __launch_bounds__(256) void k_gemm_gi(const _Float16* __restrict__ Af16, const float* __restrict__ h2,
                                                 const int* __restrict__ src, const int* __restrict__ dst,
                                                 const float* __restrict__ ea, const float* __restrict__ W,
                                                 const float* __restrict__ bias, _Float16* __restrict__ out,
                                                 int M, int Nout, int K, int mode) {
  __shared__ float As[BK][BM];
  __shared__ float Bs[BK][BN];
  int tid = threadIdx.x;
  int m0 = blockIdx.x * BM, n0 = blockIdx.y * BN;
  int lm = tid >> 2;
  int lk4 = (tid & 3) * 4;
  int bn_ = tid >> 2;
  int bk4 = (tid & 3) * 4;
  int tm = (tid >> 4) * 4, tn = (tid & 15) * 4;
  float acc[4][4] = {};
  int s_m = 0, d_m = 0;
  if (mode == 0) { s_m = src[m0 + lm]; d_m = dst[m0 + lm]; }
  for (int k0 = 0; k0 < K; k0 += BK) {
#pragma unroll
    for (int c = 0; c < 4; ++c) {
      int k = k0 + lk4 + c;
      float v = 0.f;
      if (k < K) {
        if (mode == 0) {
          if (k < 256) v = h2[(size_t)s_m * 256 + k];
          else if (k < 512) v = h2[(size_t)d_m * 256 + (k - 256)];
          else v = ea[(size_t)(m0 + lm) * 3 + (k - 512)];
        } else {
          v = (float)Af16[(size_t)k * M + (m0 + lm)];
        }
      }
      As[lk4 + c][lm] = v;
    }
#pragma unroll
    for (int c = 0; c < 4; ++c) {
      int k = k0 + bk4 + c;
      Bs[bk4 + c][bn_] = (k < K) ? W[(size_t)(n0 + bn_) * K + k] : 0.f;
    }
    __syncthreads();
#pragma unroll
    for (int kk = 0; kk < BK; ++kk) {
      float av[4], bv[4];
#pragma unroll
      for (int i = 0; i < 4; ++i) { av[i] = As[kk][tm + i]; bv[i] = Bs[kk][tn + i]; }
#pragma unroll
      for (int i = 0; i < 4; ++i)
#pragma unroll
        for (int jj = 0; jj < 4; ++jj) acc[i][jj] = fmaf(av[i], bv[jj], acc[i][jj]);
    }
    __syncthreads();
  }
#pragma unroll
  for (int i = 0; i < 4; ++i)
#pragma unroll
    for (int jj = 0; jj < 4; ++jj)
      out[(size_t)(n0 + tn + jj) * M + (m0 + tm + i)] = (_Float16)(acc[i][jj] + bias[n0 + tn + jj]);
}

// ---------------- fused pipelined GRU: scan0 | gi1 GEMM workers | scan1 ----------------
// Block 0: layer-0 scan (publishes prog0 = chunks done, flags[0]).
// Blocks 2..: gi1 GEMM workers — overwrite gi chunk c (gi0, consumed) with
//   gi1 chunk c = g0_chunk @ Wih1^T + bih1 (exact FLOP order of old k_gemm_gi
//   mode 1); publish done counts flags[64+c].
// Block 1: layer-1 scan, gated per chunk on done1[c] == NG.
// Cross-XCD visibility: per-thread __threadfence (vmcnt drain + L2 wb/inv)
// before publishing / after observing flags; flags are agent-scope atomics.
//
// Scan per-step changes vs previous round:
//  * h read as h8v (ds_read_b128): 16 LDS issues/lane/step instead of 64.
//  * dual-region h layout: half-1 stored at +272 B so the wave's two
//    broadcast addresses hit disjoint bank quads (old layout: same bank →
//    512 conflict cycles/step measured).
//  * split accumulators (2 per gate) to halve the fdot2 dependency chain.

union H8U { h8v v; h2v h[4]; };

template <int ROLE>
__device__ __forceinline__ void gru_scan_dev(const float* __restrict__ Whh, const float* __restrict__ bhh,
                                             const _Float16* __restrict__ giT, _Float16* __restrict__ gout,
                                             int T, int* __restrict__ flags, int NG) {
  int j = threadIdx.x;   // 0..511
  int uu = j >> 1;       // hidden unit 0..255
  int half = j & 1;      // K-half
  h2v wr[64], wz[64], wn[64];
  {
    const float2* r0 = (const float2*)(Whh + (size_t)uu * 256 + half * 128);
    const float2* r1 = (const float2*)(Whh + (size_t)(uu + 256) * 256 + half * 128);
    const float2* r2 = (const float2*)(Whh + (size_t)(uu + 512) * 256 + half * 128);
#pragma unroll
    for (int k = 0; k < 64; ++k) {
      float2 a = r0[k]; h2v va; va.x = (_Float16)a.x; va.y = (_Float16)a.y; wr[k] = va;
      float2 b = r1[k]; h2v vb; vb.x = (_Float16)b.x; vb.y = (_Float16)b.y; wz[k] = vb;
      float2 c = r2[k]; h2v vc; vc.x = (_Float16)c.x; vc.y = (_Float16)c.y; wn[k] = vc;
    }
  }
  float bhr = bhh[uu], bhz = bhh[uu + 256], bhn = bhh[uu + 512];
  // dual-region h buffer: h[0..127] at f16 ofs 0, h[128..255] at f16 ofs 136
  // (byte 272 → bank quad offset +4 → the two per-wave broadcast b128 reads
  // touch disjoint banks)
  __shared__ __align__(16) _Float16 hb[2][288];
  for (int i = j; i < 2 * 288; i += 512) ((_Float16*)hb)[i] = (_Float16)0.f;
  __syncthreads();
  int woff = (uu < 128) ? uu : (uu + 8);
  float h = 0.f;
  const _Float16* gr_p = giT + (size_t)uu * T;
  const _Float16* gz_p = giT + (size_t)(uu + 256) * T;
  const _Float16* gn_p = giT + (size_t)(uu + 512) * T;
  int NC = (T + GCHUNK - 1) / GCHUNK;
  for (int c = 0; c < NC; ++c) {
    int cb = c * GCHUNK;
    int ce = min(cb + GCHUNK, T);
    if (ROLE == 1) {
      if (j == 0) {
        while (__hip_atomic_load(&flags[64 + c], __ATOMIC_RELAXED, __HIP_MEMORY_SCOPE_AGENT) < NG)
          __builtin_amdgcn_s_sleep(32);
      }
      __syncthreads();
      __threadfence();   // acquire: invalidate caches before reading the chunk
    }
    h8v gr = *(const h8v*)(gr_p + cb);
    h8v gz = *(const h8v*)(gz_p + cb);
    h8v gn = *(const h8v*)(gn_p + cb);
    for (int t0 = cb; t0 < ce; t0 += 8) {
      h8v grn = gr, gzn = gz, gnn = gn;
      if (t0 + 8 < ce) {   // prefetch confined to chunk (role-1 gating)
        grn = *(const h8v*)(gr_p + t0 + 8);
        gzn = *(const h8v*)(gz_p + t0 + 8);
        gnn = *(const h8v*)(gn_p + t0 + 8);
      }
      h8v sb;
#pragma unroll
      for (int u = 0; u < 8; ++u) {
        int t = t0 + u;
        float gir = (float)gr[u], giz = (float)gz[u], gin = (float)gn[u];
        const h8v* hp8 = (const h8v*)&hb[t & 1][half * 136];
        float ar0 = 0.f, az0 = 0.f, an0 = 0.f, ar1 = 0.f, az1 = 0.f, an1 = 0.f;
#pragma unroll
        for (int k8 = 0; k8 < 8; ++k8) {
          H8U x0, x1;
          x0.v = hp8[k8];
          x1.v = hp8[k8 + 8];
#pragma unroll
          for (int q = 0; q < 4; ++q) {
            int k = k8 * 4 + q;
            ar0 = fdot2f(wr[k], x0.h[q], ar0);
            az0 = fdot2f(wz[k], x0.h[q], az0);
            an0 = fdot2f(wn[k], x0.h[q], an0);
            ar1 = fdot2f(wr[k + 32], x1.h[q], ar1);
            az1 = fdot2f(wz[k + 32], x1.h[q], az1);
            an1 = fdot2f(wn[k + 32], x1.h[q], an1);
          }
        }
        float ar = ar0 + ar1, az = az0 + az1, an = an0 + an1;
        ar += __shfl_xor(ar, 1);
        az += __shfl_xor(az, 1);
        an += __shfl_xor(an, 1);
        ar += bhr; az += bhz; an += bhn;
        float r = sigf(gir + ar);
        float zt = sigf(giz + az);
        float nn = tanhfast(gin + r * an);
        h = (1.f - zt) * nn + zt * h;
        sb[u] = (_Float16)h;
        if (half == 0) hb[(t & 1) ^ 1][woff] = (_Float16)h;
        __syncthreads();
      }
      if (half == 0) *(h8v*)(gout + (size_t)uu * T + t0) = sb;
      gr = grn; gz = gzn; gn = gnn;
    }
    if (ROLE == 0) {
      __threadfence();   // each thread drains + writes back its g0 stores
      __syncthreads();
      if (j == 0) __hip_atomic_store(&flags[0], c + 1, __ATOMIC_RELAXED, __HIP_MEMORY_SCOPE_AGENT);
    }
  }
}

// gi1 worker: 512 threads, 64x64x16 tiles, 2x4 microtile.
__device__ __forceinline__ void gi1_worker(const _Float16* __restrict__ g0, const float* __restrict__ Wih1,
                                           const float* __restrict__ bih1, _Float16* __restrict__ giT,
                                           int T, int w, int NG, int* __restrict__ flags) {
  __shared__ float As[16][64];
  __shared__ float Bs[16][66];
  int tid = threadIdx.x;
  int lk = tid >> 5, lm = (tid & 31) * 2;    // A load: [k][m], 2 per thread
  int bk = (tid & 7) * 2, bn = tid >> 3;     // B load: [k][n], 2 per thread
  int tm = (tid >> 4) * 2, tn = (tid & 15) * 4;
  int NC = (T + GCHUNK - 1) / GCHUNK;
  for (int c = 0; c < NC; ++c) {
    if (tid == 0) {
      while (__hip_atomic_load(&flags[0], __ATOMIC_RELAXED, __HIP_MEMORY_SCOPE_AGENT) < c + 1)
        __builtin_amdgcn_s_sleep(32);
    }
    __syncthreads();
    __threadfence();   // acquire: g0 chunk may be stale in this XCD's L2
    int cb = c * GCHUNK;
    int clen = min(GCHUNK, T - cb);
    int mt = (clen + 63) >> 6;
    int ntile = mt * 12;   // 768/64 feature tiles
    for (int tile = w; tile < ntile; tile += NG) {
      int m0 = cb + (tile % mt) * 64;
      int n0 = (tile / mt) * 64;
      float acc[2][4] = {};
      for (int k0 = 0; k0 < 256; k0 += 16) {
        int m = m0 + lm;
        float ax = 0.f, ay = 0.f;
        if (m + 1 < T) {
          h2v hv = *(const h2v*)(g0 + (size_t)(k0 + lk) * T + m);
          ax = (float)hv.x; ay = (float)hv.y;
        } else if (m < T) {
          ax = (float)g0[(size_t)(k0 + lk) * T + m];
        }
        As[lk][lm] = ax;
        As[lk][lm + 1] = ay;
        float2 bv2 = *(const float2*)(Wih1 + (size_t)(n0 + bn) * 256 + k0 + bk);
        Bs[bk][bn] = bv2.x;
        Bs[bk + 1][bn] = bv2.y;
        __syncthreads();
#pragma unroll
        for (int kk = 0; kk < 16; ++kk) {
          float a0 = As[kk][tm], a1 = As[kk][tm + 1];
          float b0 = Bs[kk][tn], b1 = Bs[kk][tn + 1], b2v = Bs[kk][tn + 2], b3 = Bs[kk][tn + 3];
          acc[0][0] = fmaf(a0, b0, acc[0][0]);
          acc[0][1] = fmaf(a0, b1, acc[0][1]);
          acc[0][2] = fmaf(a0, b2v, acc[0][2]);
          acc[0][3] = fmaf(a0, b3, acc[0][3]);
          acc[1][0] = fmaf(a1, b0, acc[1][0]);
          acc[1][1] = fmaf(a1, b1, acc[1][1]);
          acc[1][2] = fmaf(a1, b2v, acc[1][2]);
          acc[1][3] = fmaf(a1, b3, acc[1][3]);
        }
        __syncthreads();
      }
#pragma unroll
      for (int i = 0; i < 2; ++i) {
        int m = m0 + tm + i;
        if (m < T) {
#pragma unroll
          for (int q = 0; q < 4; ++q)
            giT[(size_t)(n0 + tn + q) * T + m] = (_Float16)(acc[i][q] + bih1[n0 + tn + q]);
        }
      }
    }
    __threadfence();   // release: flush gi1 chunk stores before counting done
    __syncthreads();
    if (tid == 0) __hip_atomic_fetch_add(&flags[64 + c], 1, __ATOMIC_RELAXED, __HIP_MEMORY_SCOPE_AGENT);
  }
}

__global__ __launch_bounds__(512, 2) void k_fused_gru(const float* __restrict__ Whh0, const float* __restrict__ bhh0,
                                                      const float* __restrict__ Whh1, const float* __restrict__ bhh1,
                                                      const float* __restrict__ Wih1, const float* __restrict__ bih1,
                                                      _Float16* __restrict__ gi, _Float16* __restrict__ g0,
                                                      _Float16* __restrict__ g1, int T, int* __restrict__ flags) {
  int b = blockIdx.x;
  int NG = (int)gridDim.x - 2;
  if (b == 0)
    gru_scan_dev<0>(Whh0, bhh0, gi, g0, T, flags, NG);
  else if (b == 1)
    gru_scan_dev<1>(Whh1, bhh1, gi, g1, T, flags, NG);
  else
    gi1_worker(g0, Wih1, bih1, gi, T, b - 2, NG, flags);
}

// ---------------- final MLP: out[t] = Wlin2 . relu(Wlin1 . g1_t + blin1) + blin2 ----------------

__global__ __launch_bounds__(128) void k_final(const _Float16* __restrict__ g1T, const float* __restrict__ Wlin1,
                                               const float* __restrict__ blin1, const float* __restrict__ Wlin2,
                                               const float* __restrict__ blin2, float* __restrict__ out, int E) {
  int j = threadIdx.x;  // 0..127
  float w[256];
#pragma unroll
  for (int k = 0; k < 256; ++k) w[k] = Wlin1[(size_t)j * 256 + k];
  float bj = blin1[j], w2j = Wlin2[j], b2v = blin2[0];
  __shared__ float gsf[256];
  __shared__ float red[128];
  for (int t = blockIdx.x; t < E; t += gridDim.x) {
    gsf[j] = (float)g1T[(size_t)j * E + t];
    gsf[j + 128] = (float)g1T[(size_t)(j + 128) * E + t];
    __syncthreads();
    float acc = 0.f;
#pragma unroll
    for (int k = 0; k < 256; ++k) acc = fmaf(w[k], gsf[k], acc);
    float v = fmaxf(acc + bj, 0.f) * w2j;
    red[j] = v;
    __syncthreads();
    for (int s = 64; s > 0; s >>= 1) {
      if (j < s) red[j] += red[j + s];
      __syncthreads();
    }
    if (j == 0) out[t] = red[0] + b2v;
    __syncthreads();
  }
}

// ---------------- launch ----------------

extern "C" void kernel_launch(void* const* d_in, const int* in_sizes, int n_in,
                              void* d_out, int out_size, void* d_ws, size_t ws_size,
                              hipStream_t stream) {
  (void)n_in; (void)out_size; (void)ws_size;
  const float* x = (const float*)d_in[0];
  const int* ei = (const int*)d_in[1];
  const float* ea = (const float*)d_in[2];
  const float* W1 = (const float*)d_in[3];
  const float* as1 = (const float*)d_in[4];
  const float* ad1 = (const float*)d_in[5];
  const float* b1 = (const float*)d_in[6];
  const float* gamma1 = (const float*)d_in[7];
  const float* beta1 = (const float*)d_in[8];
  const float* mean1 = (const float*)d_in[9];
  const float* var1 = (const float*)d_in[10];
  const float* W2 = (const float*)d_in[11];
  const float* as2 = (const float*)d_in[12];
  const float* ad2 = (const float*)d_in[13];
  const float* b2 = (const float*)d_in[14];
  const float* gamma2 = (const float*)d_in[15];
  const float* beta2 = (const float*)d_in[16];
  const float* mean2 = (const float*)d_in[17];
  const float* var2 = (const float*)d_in[18];
  const float* Wih0 = (const float*)d_in[19];
  const float* Whh0 = (const float*)d_in[20];
  const float* bih0 = (const float*)d_in[21];
  const float* bhh0 = (const float*)d_in[22];
  const float* Wih1 = (const float*)d_in[23];
  const float* Whh1 = (const float*)d_in[24];
  const float* bih1 = (const float*)d_in[25];
  const float* bhh1 = (const float*)d_in[26];
  const float* Wlin1 = (const float*)d_in[27];
  const float* blin1 = (const float*)d_in[28];
  const float* Wlin2 = (const float*)d_in[29];
  const float* blin2 = (const float*)d_in[30];

  int N = in_sizes[0];
  int E = in_sizes[1] / 2;
  const int* src = ei;
  const int* dst = ei + E;

  char* wsp = (char*)d_ws;
  size_t off = 0;
  auto carve = [&](size_t bytes) -> void* {
    void* p = wsp + off;
    off = (off + bytes + 255) & ~(size_t)255;
    return p;
  };
  float* c12 = (float*)carve(2 * sizeof(float));
  float* a1s = (float*)carve((size_t)N * 4);
  float* a1d = (float*)carve((size_t)N * 4);
  unsigned* m1 = (unsigned*)carve((size_t)N * 4);
  float* z1 = (float*)carve((size_t)N * 4);
  float* uacc = (float*)carve((size_t)N * 4);
  float* h1 = (float*)carve((size_t)N * 256 * 4);
  float* xw2 = (float*)carve((size_t)N * 256 * 4);
  float* a2s = (float*)carve((size_t)N * 4);
  float* a2d = (float*)carve((size_t)N * 4);
  unsigned* m2 = (unsigned*)carve((size_t)N * 4);
  float* z2 = (float*)carve((size_t)N * 4);
  float* acc2 = (float*)carve((size_t)N * 256 * 4);          // becomes h2 in-place
  _Float16* gi = (_Float16*)carve((size_t)E * 768 * 2);      // feature-major [768, E]; gi0, overwritten chunkwise by gi1
  _Float16* g0 = (_Float16*)carve((size_t)E * 256 * 2);      // feature-major [256, E]
  _Float16* g1 = (_Float16*)carve((size_t)E * 256 * 2);      // feature-major [256, E]
  int NCh = (E + GCHUNK - 1) / GCHUNK;
  int flagN = 64 + NCh;                                      // flags[0]=prog0, flags[64+c]=done1[c]
  int* flags = (int*)carve((size_t)flagN * 4);

  hipMemsetAsync(m1, 0, (size_t)N * 4, stream);
  hipMemsetAsync(z1, 0, (size_t)N * 4, stream);
  hipMemsetAsync(uacc, 0, (size_t)N * 4, stream);
  hipMemsetAsync(m2, 0, (size_t)N * 4, stream);
  hipMemsetAsync(z2, 0, (size_t)N * 4, stream);
  hipMemsetAsync(acc2, 0, (size_t)N * 256 * 4, stream);
  hipMemsetAsync(flags, 0, (size_t)flagN * 4, stream);

  int eb = (E + N + 255) / 256;

  k_prep_c<<<1, 256, 0, stream>>>(W1, as1, ad1, c12);
  k_a1<<<(N + 255) / 256, 256, 0, stream>>>(x, c12, a1s, a1d, N);
  k_edge_max<<<eb, 256, 0, stream>>>(a1s, a1d, m1, src, dst, E, N);
  k_gat1_edge_sum<<<eb, 256, 0, stream>>>(a1s, a1d, m1, src, dst, x, z1, uacc, E, N);
  k_gat1_node<<<N, 256, 0, stream>>>(uacc, z1, W1, b1, gamma1, beta1, mean1, var1, h1);

  dim3 gx((N + BM - 1) / BM, 256 / BN);
  k_gemm_f32<<<gx, 256, 0, stream>>>(h1, W2, xw2, N, 256, 256);
  k_rowdots<<<N, 256, 0, stream>>>(xw2, as2, ad2, a2s, a2d);
  k_edge_max<<<eb, 256, 0, stream>>>(a2s, a2d, m2, src, dst, E, N);
  k_gat2_scatter<<<4096, 256, 0, stream>>>(a2s, a2d, m2, src, dst, xw2, z2, acc2, E, N);
  k_gat2_node<<<N, 256, 0, stream>>>(acc2, z2, b2, gamma2, beta2, mean2, var2);

  dim3 gg(E / BM, 768 / BN);
  k_gemm_gi<<<gg, 256, 0, stream>>>(nullptr, acc2, src, dst, ea, Wih0, bih0, gi, E, 768, 515, 0);

  // fused pipelined GRU: block0=scan0, block1=scan1, blocks2..63 = gi1 workers
  // (64 blocks << 256 CUs -> all co-resident; scan0 waits on nobody -> no deadlock)
  k_fused_gru<<<64, 512, 0, stream>>>(Whh0, bhh0, Whh1, bhh1, Wih1, bih1, gi, g0, g1, E, flags);

  k_final<<<1024, 128, 0, stream>>>(g1, Wlin1, blin1, Wlin2, blin2, (float*)d_out, E);
}

// Round 2
// 90386.841 us; speedup vs baseline: 1.7159x; 1.0027x over previous
//
#include <hip/hip_runtime.h>
#include <cstdint>
#include <cstddef>

typedef _Float16 h2v __attribute__((ext_vector_type(2)));
typedef _Float16 h8v __attribute__((ext_vector_type(8)));

#define NEG_SLOPE 0.2f
#define BN_EPS 1e-5f
#define BM 64
#define BN 64
#define BK 16
#define GCHUNK 1024   // GRU pipeline chunk (steps); must be multiple of 8
#define NW0 40        // gi0 GEMM workers (h2-gather @ Wih0^T, K=515)
#define NW1 22        // gi1 GEMM workers (g0 @ Wih1^T, K=256)
#define NBLK (2 + NW0 + NW1)

__device__ __forceinline__ float lrelu(float x) { return x > 0.f ? x : NEG_SLOPE * x; }

__device__ __forceinline__ unsigned fenc(float f) {
  unsigned b = __float_as_uint(f);
  return (b & 0x80000000u) ? ~b : (b | 0x80000000u);
}
__device__ __forceinline__ float fdec(unsigned u) {
  return (u & 0x80000000u) ? __uint_as_float(u & 0x7fffffffu) : __uint_as_float(~u);
}

__device__ __forceinline__ float fdot2f(h2v a, h2v b, float c) {
#if __has_builtin(__builtin_amdgcn_fdot2)
  return __builtin_amdgcn_fdot2(a, b, c, false);
#else
  return c + (float)a.x * (float)b.x + (float)a.y * (float)b.y;
#endif
}
__device__ __forceinline__ float sigf(float x) { return 1.f / (1.f + __expf(-x)); }
__device__ __forceinline__ float tanhfast(float x) {
  x = fminf(fmaxf(x, -20.f), 20.f);
  float e = __expf(2.f * x);
  return (e - 1.f) / (e + 1.f);
}

// Per-step barrier for the GRU scan: only LDS ordering is required for the
// h hand-off (LDS is CU-local). __syncthreads() would drain vmcnt(0) too,
// serializing the gi prefetch / gout store latency into the recurrence.
__device__ __forceinline__ void step_barrier() {
  __builtin_amdgcn_sched_barrier(0);
  asm volatile("s_waitcnt lgkmcnt(0)" ::: "memory");
  __builtin_amdgcn_s_barrier();
  __builtin_amdgcn_sched_barrier(0);
}

// ---------------- GAT layer 1 (rank-1 collapse) ----------------

__global__ __launch_bounds__(256) void k_prep_c(const float* __restrict__ W1,
                                                const float* __restrict__ as1,
                                                const float* __restrict__ ad1,
                                                float* __restrict__ c12) {
  __shared__ float r1[256], r2[256];
  int j = threadIdx.x;
  float wv = W1[j];
  r1[j] = wv * as1[j];
  r2[j] = wv * ad1[j];
  __syncthreads();
  for (int s = 128; s > 0; s >>= 1) {
    if (j < s) { r1[j] += r1[j + s]; r2[j] += r2[j + s]; }
    __syncthreads();
  }
  if (j == 0) { c12[0] = r1[0]; c12[1] = r2[0]; }
}

__global__ __launch_bounds__(256) void k_a1(const float* __restrict__ x, const float* __restrict__ c12,
                                            float* __restrict__ a1s, float* __restrict__ a1d, int N) {
  int i = blockIdx.x * 256 + threadIdx.x;
  if (i < N) {
    float xv = x[i];
    a1s[i] = c12[0] * xv;
    a1d[i] = c12[1] * xv;
  }
}

__global__ __launch_bounds__(256) void k_edge_max(const float* __restrict__ as_, const float* __restrict__ ad_,
                                                  unsigned* __restrict__ menc, const int* __restrict__ src,
                                                  const int* __restrict__ dst, int E, int N) {
  int i = blockIdx.x * 256 + threadIdx.x;
  if (i >= E + N) return;
  int s, d;
  if (i < E) { s = src[i]; d = dst[i]; } else { s = i - E; d = s; }
  float e = lrelu(as_[s] + ad_[d]);
  atomicMax(&menc[d], fenc(e));
}

__global__ __launch_bounds__(256) void k_gat1_edge_sum(const float* __restrict__ as_, const float* __restrict__ ad_,
                                                       const unsigned* __restrict__ menc, const int* __restrict__ src,
                                                       const int* __restrict__ dst, const float* __restrict__ x,
                                                       float* __restrict__ z, float* __restrict__ uacc, int E, int N) {
  int i = blockIdx.x * 256 + threadIdx.x;
  if (i >= E + N) return;
  int s, d;
  if (i < E) { s = src[i]; d = dst[i]; } else { s = i - E; d = s; }
  float e = lrelu(as_[s] + ad_[d]);
  float p = __expf(e - fdec(menc[d]));
  atomicAdd(&z[d], p);
  atomicAdd(&uacc[d], p * x[s]);
}

__global__ __launch_bounds__(256) void k_gat1_node(const float* __restrict__ uacc, const float* __restrict__ z1,
                                                   const float* __restrict__ W1, const float* __restrict__ b1,
                                                   const float* __restrict__ gamma, const float* __restrict__ beta,
                                                   const float* __restrict__ mean, const float* __restrict__ var,
                                                   float* __restrict__ h1) {
  int n = blockIdx.x, j = threadIdx.x;
  float u = uacc[n] / z1[n];
  float v = u * W1[j] + b1[j];
  v = (v - mean[j]) * rsqrtf(var[j] + BN_EPS) * gamma[j] + beta[j];
  h1[(size_t)n * 256 + j] = fmaxf(v, 0.f);
}

// ---------------- generic fp32 tiled GEMM: C[M,N] = A[M,K] * B[K,N] ----------------

__global__ __launch_bounds__(256) void k_gemm_f32(const float* __restrict__ A, const float* __restrict__ B,
                                                  float* __restrict__ C, int M, int N, int K) {
  __shared__ float As[BK][BM];
  __shared__ float Bs[BK][BN];
  int tid = threadIdx.x;
  int m0 = blockIdx.x * BM, n0 = blockIdx.y * BN;
  int lm = tid >> 2;
  int lk4 = (tid & 3) * 4;
  int bn_ = tid & 63;
  int bkq = (tid >> 6) * 4;
  int tm = (tid >> 4) * 4, tn = (tid & 15) * 4;
  float acc[4][4] = {};
  for (int k0 = 0; k0 < K; k0 += BK) {
    float4 av4 = make_float4(0.f, 0.f, 0.f, 0.f);
    if (m0 + lm < M) av4 = *(const float4*)(A + (size_t)(m0 + lm) * K + k0 + lk4);
    As[lk4 + 0][lm] = av4.x;
    As[lk4 + 1][lm] = av4.y;
    As[lk4 + 2][lm] = av4.z;
    As[lk4 + 3][lm] = av4.w;
#pragma unroll
    for (int c = 0; c < 4; ++c) {
      int k = k0 + bkq + c;
      Bs[bkq + c][bn_] = (k < K) ? B[(size_t)k * N + n0 + bn_] : 0.f;
    }
    __syncthreads();
#pragma unroll
    for (int kk = 0; kk < BK; ++kk) {
      float av[4], bv[4];
#pragma unroll
      for (int i = 0; i < 4; ++i) { av[i] = As[kk][tm + i]; bv[i] = Bs[kk][tn + i]; }
#pragma unroll
      for (int i = 0; i < 4; ++i)
#pragma unroll
        for (int jj = 0; jj < 4; ++jj) acc[i][jj] = fmaf(av[i], bv[jj], acc[i][jj]);
    }
    __syncthreads();
  }
#pragma unroll
  for (int i = 0; i < 4; ++i) {
    int m = m0 + tm + i;
    if (m < M) {
      float4 v = make_float4(acc[i][0], acc[i][1], acc[i][2], acc[i][3]);
      *(float4*)(C + (size_t)m * N + n0 + tn) = v;
    }
  }
}

// ---------------- row dots for GAT2 attention scalars ----------------

__global__ __launch_bounds__(256) void k_rowdots(const float* __restrict__ xw2, const float* __restrict__ as2,
                                                 const float* __restrict__ ad2, float* __restrict__ a2s,
                                                 float* __restrict__ a2d) {
  __shared__ float r1[256], r2[256];
  int n = blockIdx.x, j = threadIdx.x;
  float v = xw2[(size_t)n * 256 + j];
  r1[j] = v * as2[j];
  r2[j] = v * ad2[j];
  __syncthreads();
  for (int s = 128; s > 0; s >>= 1) {
    if (j < s) { r1[j] += r1[j + s]; r2[j] += r2[j + s]; }
    __syncthreads();
  }
  if (j == 0) { a2s[n] = r1[0]; a2d[n] = r2[0]; }
}

__global__ __launch_bounds__(256) void k_gat2_scatter(const float* __restrict__ a2s, const float* __restrict__ a2d,
                                                      const unsigned* __restrict__ m2, const int* __restrict__ src,
                                                      const int* __restrict__ dst, const float* __restrict__ xw2,
                                                      float* __restrict__ z2, float* __restrict__ acc2, int E, int N) {
  int j = threadIdx.x;
  for (int i = blockIdx.x; i < E + N; i += gridDim.x) {
    int s, d;
    if (i < E) { s = src[i]; d = dst[i]; } else { s = i - E; d = s; }
    float e = lrelu(a2s[s] + a2d[d]);
    float p = __expf(e - fdec(m2[d]));
    if (j == 0) atomicAdd(&z2[d], p);
    atomicAdd(&acc2[(size_t)d * 256 + j], p * xw2[(size_t)s * 256 + j]);
  }
}

__global__ __launch_bounds__(256) void k_gat2_node(float* __restrict__ acc2, const float* __restrict__ z2,
                                                   const float* __restrict__ b2, const float* __restrict__ gamma,
                                                   const float* __restrict__ beta, const float* __restrict__ mean,
                                                   const float* __restrict__ var) {
  int n = blockIdx.x, j = threadIdx.x;
  size_t idx = (size_t)n * 256 + j;
  float v = acc2[idx] / z2[n] + b2[j];
  v = (v - mean[j]) * rsqrtf(var[j] + BN_EPS) * gamma[j] + beta[j];
  acc2[idx] = fmaxf(v, 0.f);
}

// ---------------- fused pipelined GRU ----------------
// Roles (one grid, NBLK=64 blocks, all co-resident on 256 CUs):
//   block 0            : layer-0 scan; waits done0[c]==NW0; publishes prog0=c+1
//   block 1            : layer-1 scan; waits done1[c]==NW1
//   blocks 2..2+NW0-1  : gi0 workers (wait NOTHING; h2/src/dst/ea ready at
//                        kernel entry) -> write gi slot c, bump done0[c]
//   rest (NW1)         : gi1 workers; wait prog0>=c+1 (scan0 consumed gi0[c])
//                        -> overwrite gi slot c in place, bump done1[c]
// DAG: gi0 -> scan0 -> gi1 -> scan1; no cycles, no deadlock.
// Cross-XCD visibility: per-thread __threadfence (release: drain stores +
// L2 wb; acquire: invalidate) around relaxed agent-scope flag atomics.
// flags layout: [0]=prog0, [8..8+NC)=done0, [8+NC..8+2NC)=done1.

union H8U { h8v v; h2v h[4]; };

template <int ROLE>
__device__ __forceinline__ void gru_scan_dev(const float* __restrict__ Whh, const float* __restrict__ bhh,
                                             const _Float16* __restrict__ giT, _Float16* __restrict__ gout,
                                             int T, int* __restrict__ prog, int* __restrict__ done, int ndone) {
  int j = threadIdx.x;   // 0..511
  int uu = j >> 1;       // hidden unit 0..255
  int half = j & 1;      // K-half
  h2v wr[64], wz[64], wn[64];
  {
    const float2* r0 = (const float2*)(Whh + (size_t)uu * 256 + half * 128);
    const float2* r1 = (const float2*)(Whh + (size_t)(uu + 256) * 256 + half * 128);
    const float2* r2 = (const float2*)(Whh + (size_t)(uu + 512) * 256 + half * 128);
#pragma unroll
    for (int k = 0; k < 64; ++k) {
      float2 a = r0[k]; h2v va; va.x = (_Float16)a.x; va.y = (_Float16)a.y; wr[k] = va;
      float2 b = r1[k]; h2v vb; vb.x = (_Float16)b.x; vb.y = (_Float16)b.y; wz[k] = vb;
      float2 c = r2[k]; h2v vc; vc.x = (_Float16)c.x; vc.y = (_Float16)c.y; wn[k] = vc;
    }
  }
  float bhr = bhh[uu], bhz = bhh[uu + 256], bhn = bhh[uu + 512];
  // dual-region h buffer: half-1 region at +272 B so the wave's two
  // broadcast b128 addresses hit disjoint bank quads.
  __shared__ __align__(16) _Float16 hb[2][288];
  for (int i = j; i < 2 * 288; i += 512) ((_Float16*)hb)[i] = (_Float16)0.f;
  __syncthreads();
  int woff = (uu < 128) ? uu : (uu + 8);
  float h = 0.f;
  const _Float16* gr_p = giT + (size_t)uu * T;
  const _Float16* gz_p = giT + (size_t)(uu + 256) * T;
  const _Float16* gn_p = giT + (size_t)(uu + 512) * T;
  int NC = (T + GCHUNK - 1) / GCHUNK;
  for (int c = 0; c < NC; ++c) {
    int cb = c * GCHUNK;
    int ce = min(cb + GCHUNK, T);
    // gate: chunk c of this layer's gi is ready
    if (j == 0) {
      while (__hip_atomic_load(&done[c], __ATOMIC_RELAXED, __HIP_MEMORY_SCOPE_AGENT) < ndone)
        __builtin_amdgcn_s_sleep(32);
    }
    __syncthreads();
    __threadfence();   // acquire: invalidate caches before reading the chunk
    h8v gr = *(const h8v*)(gr_p + cb);
    h8v gz = *(const h8v*)(gz_p + cb);
    h8v gn = *(const h8v*)(gn_p + cb);
    for (int t0 = cb; t0 < ce; t0 += 8) {
      h8v grn = gr, gzn = gz, gnn = gn;
      if (t0 + 8 < ce) {   // prefetch confined to chunk
        grn = *(const h8v*)(gr_p + t0 + 8);
        gzn = *(const h8v*)(gz_p + t0 + 8);
        gnn = *(const h8v*)(gn_p + t0 + 8);
      }
      h8v sb;
#pragma unroll
      for (int u = 0; u < 8; ++u) {
        int t = t0 + u;
        float gir = (float)gr[u], giz = (float)gz[u], gin = (float)gn[u];
        const h8v* hp8 = (const h8v*)&hb[t & 1][half * 136];
        float ar0 = 0.f, az0 = 0.f, an0 = 0.f, ar1 = 0.f, az1 = 0.f, an1 = 0.f;
#pragma unroll
        for (int k8 = 0; k8 < 8; ++k8) {
          H8U x0, x1;
          x0.v = hp8[k8];
          x1.v = hp8[k8 + 8];
#pragma unroll
          for (int q = 0; q < 4; ++q) {
            int k = k8 * 4 + q;
            ar0 = fdot2f(wr[k], x0.h[q], ar0);
            az0 = fdot2f(wz[k], x0.h[q], az0);
            an0 = fdot2f(wn[k], x0.h[q], an0);
            ar1 = fdot2f(wr[k + 32], x1.h[q], ar1);
            az1 = fdot2f(wz[k + 32], x1.h[q], az1);
            an1 = fdot2f(wn[k + 32], x1.h[q], an1);
          }
        }
        float ar = ar0 + ar1, az = az0 + az1, an = an0 + an1;
        ar += __shfl_xor(ar, 1);
        az += __shfl_xor(az, 1);
        an += __shfl_xor(an, 1);
        ar += bhr; az += bhz; an += bhn;
        float r = sigf(gir + ar);
        float zt = sigf(giz + az);
        float nn = tanhfast(gin + r * an);
        h = (1.f - zt) * nn + zt * h;
        sb[u] = (_Float16)h;
        if (half == 0) hb[(t & 1) ^ 1][woff] = (_Float16)h;
        step_barrier();   // lgkm-only: gi prefetch/gout stores stay in flight
      }
      if (half == 0) *(h8v*)(gout + (size_t)uu * T + t0) = sb;
      gr = grn; gz = gzn; gn = gnn;
    }
    if (ROLE == 0) {
      __threadfence();   // release: drain this thread's g0 stores + L2 wb
      __syncthreads();
      if (j == 0) __hip_atomic_store(&prog[0], c + 1, __ATOMIC_RELAXED, __HIP_MEMORY_SCOPE_AGENT);
    }
  }
}

// gi0 worker: gi0[:,m] = [h2[src[m]], h2[dst[m]], ea[m]] @ Wih0^T + bih0  (K=515)
// FLOP order (ascending k, fp32 fmaf) identical to the old k_gemm_gi mode 0.
__device__ __forceinline__ void gi0_worker(const float* __restrict__ h2, const int* __restrict__ src,
                                           const int* __restrict__ dst, const float* __restrict__ ea,
                                           const float* __restrict__ W, const float* __restrict__ bias,
                                           _Float16* __restrict__ giT, int T, int w,
                                           int* __restrict__ done, int NC) {
  __shared__ float As0[16][64];
  __shared__ float Bs0[16][66];
  int tid = threadIdx.x;
  int lk = tid >> 5, lm2 = (tid & 31) * 2;   // A load: [k][m], 2 m's per thread
  int bn = tid >> 3, bk2 = (tid & 7) * 2;    // B load: [k][n], 2 k's per thread
  int tm = (tid >> 4) * 2, tn = (tid & 15) * 4;
  for (int c = 0; c < NC; ++c) {
    int cb = c * GCHUNK;
    int clen = min(GCHUNK, T - cb);
    int mt = (clen + 63) >> 6;
    int ntile = mt * 12;   // 768/64 feature tiles
    for (int tile = w; tile < ntile; tile += NW0) {
      int m0 = cb + (tile % mt) * 64;
      int n0 = (tile / mt) * 64;
      int mA0 = m0 + lm2, mA1 = mA0 + 1;
      int s0 = (mA0 < T) ? src[mA0] : 0, d0 = (mA0 < T) ? dst[mA0] : 0;
      int s1 = (mA1 < T) ? src[mA1] : 0, d1 = (mA1 < T) ? dst[mA1] : 0;
      float acc[2][4] = {};
      for (int k0 = 0; k0 < 515; k0 += 16) {
        int k = k0 + lk;
        float a0, a1;
        if (k < 256) {
          a0 = h2[(size_t)s0 * 256 + k];
          a1 = h2[(size_t)s1 * 256 + k];
        } else if (k < 512) {
          a0 = h2[(size_t)d0 * 256 + (k - 256)];
          a1 = h2[(size_t)d1 * 256 + (k - 256)];
        } else {
          a0 = (k < 515 && mA0 < T) ? ea[(size_t)mA0 * 3 + (k - 512)] : 0.f;
          a1 = (k < 515 && mA1 < T) ? ea[(size_t)mA1 * 3 + (k - 512)] : 0.f;
        }
        As0[lk][lm2] = a0;
        As0[lk][lm2 + 1] = a1;
        Bs0[bk2][bn] = (k0 + bk2 < 515) ? W[(size_t)(n0 + bn) * 515 + k0 + bk2] : 0.f;
        Bs0[bk2 + 1][bn] = (k0 + bk2 + 1 < 515) ? W[(size_t)(n0 + bn) * 515 + k0 + bk2 + 1] : 0.f;
        __syncthreads();
#pragma unroll
        for (int kk = 0; kk < 16; ++kk) {
          float a0v = As0[kk][tm], a1v = As0[kk][tm + 1];
          float b0 = Bs0[kk][tn], b1 = Bs0[kk][tn + 1], b2v = Bs0[kk][tn + 2], b3 = Bs0[kk][tn + 3];
          acc[0][0] = fmaf(a0v, b0, acc[0][0]);
          acc[0][1] = fmaf(a0v, b1, acc[0][1]);
          acc[0][2] = fmaf(a0v, b2v, acc[0][2]);
          acc[0][3] = fmaf(a0v, b3, acc[0][3]);
          acc[1][0] = fmaf(a1v, b0, acc[1][0]);
          acc[1][1] = fmaf(a1v, b1, acc[1][1]);
          acc[1][2] = fmaf(a1v, b2v, acc[1][2]);
          acc[1][3] = fmaf(a1v, b3, acc[1][3]);
        }
        __syncthreads();
      }
#pragma unroll
      for (int i = 0; i < 2; ++i) {
        int m = m0 + tm + i;
        if (m < T) {
#pragma unroll
          for (int q = 0; q < 4; ++q)
            giT[(size_t)(n0 + tn + q) * T + m] = (_Float16)(acc[i][q] + bias[n0 + tn + q]);
        }
      }
    }
    __threadfence();   // release: flush gi0 chunk stores
    __syncthreads();
    if (tid == 0) __hip_atomic_fetch_add(&done[c], 1, __ATOMIC_RELAXED, __HIP_MEMORY_SCOPE_AGENT);
  }
}

// gi1 worker: overwrites gi slot c (gi0 consumed) with g0_chunk @ Wih1^T + bih1.
__device__ __forceinline__ void gi1_worker(const _Float16* __restrict__ g0, const float* __restrict__ Wih1,
                                           const float* __restrict__ bih1, _Float16* __restrict__ giT,
                                           int T, int w, int* __restrict__ prog, int* __restrict__ done, int NC) {
  __shared__ float As1[16][64];
  __shared__ float Bs1[16][66];
  int tid = threadIdx.x;
  int lk = tid >> 5, lm = (tid & 31) * 2;
  int bk = (tid & 7) * 2, bn = tid >> 3;
  int tm = (tid >> 4) * 2, tn = (tid & 15) * 4;
  for (int c = 0; c < NC; ++c) {
    if (tid == 0) {
      while (__hip_atomic_load(&prog[0], __ATOMIC_RELAXED, __HIP_MEMORY_SCOPE_AGENT) < c + 1)
        __builtin_amdgcn_s_sleep(32);
    }
    __syncthreads();
    __threadfence();   // acquire: g0 chunk may be stale in this XCD's L2
    int cb = c * GCHUNK;
    int clen = min(GCHUNK, T - cb);
    int mt = (clen + 63) >> 6;
    int ntile = mt * 12;
    for (int tile = w; tile < ntile; tile += NW1) {
      int m0 = cb + (tile % mt) * 64;
      int n0 = (tile / mt) * 64;
      float acc[2][4] = {};
      for (int k0 = 0; k0 < 256; k0 += 16) {
        int m = m0 + lm;
        float ax = 0.f, ay = 0.f;
        if (m + 1 < T) {
          h2v hv = *(const h2v*)(g0 + (size_t)(k0 + lk) * T + m);
          ax = (float)hv.x; ay = (float)hv.y;
        } else if (m < T) {
          ax = (float)g0[(size_t)(k0 + lk) * T + m];
        }
        As1[lk][lm] = ax;
        As1[lk][lm + 1] = ay;
        float2 bv2 = *(const float2*)(Wih1 + (size_t)(n0 + bn) * 256 + k0 + bk);
        Bs1[bk][bn] = bv2.x;
        Bs1[bk + 1][bn] = bv2.y;
        __syncthreads();
#pragma unroll
        for (int kk = 0; kk < 16; ++kk) {
          float a0 = As1[kk][tm], a1 = As1[kk][tm + 1];
          float b0 = Bs1[kk][tn], b1 = Bs1[kk][tn + 1], b2v = Bs1[kk][tn + 2], b3 = Bs1[kk][tn + 3];
          acc[0][0] = fmaf(a0, b0, acc[0][0]);
          acc[0][1] = fmaf(a0, b1, acc[0][1]);
          acc[0][2] = fmaf(a0, b2v, acc[0][2]);
          acc[0][3] = fmaf(a0, b3, acc[0][3]);
          acc[1][0] = fmaf(a1, b0, acc[1][0]);
          acc[1][1] = fmaf(a1, b1, acc[1][1]);
          acc[1][2] = fmaf(a1, b2v, acc[1][2]);
          acc[1][3] = fmaf(a1, b3, acc[1][3]);
        }
        __syncthreads();
      }
#pragma unroll
      for (int i = 0; i < 2; ++i) {
        int m = m0 + tm + i;
        if (m < T) {
#pragma unroll
          for (int q = 0; q < 4; ++q)
            giT[(size_t)(n0 + tn + q) * T + m] = (_Float16)(acc[i][q] + bih1[n0 + tn + q]);
        }
      }
    }
    __threadfence();   // release: flush gi1 chunk stores
    __syncthreads();
    if (tid == 0) __hip_atomic_fetch_add(&done[c], 1, __ATOMIC_RELAXED, __HIP_MEMORY_SCOPE_AGENT);
  }
}

__global__ __launch_bounds__(512, 2) void k_fused_gru(const float* __restrict__ Whh0, const float* __restrict__ bhh0,
                                                      const float* __restrict__ Whh1, const float* __restrict__ bhh1,
                                                      const float* __restrict__ h2, const int* __restrict__ src,
                                                      const int* __restrict__ dst, const float* __restrict__ ea,
                                                      const float* __restrict__ Wih0, const float* __restrict__ bih0,
                                                      const float* __restrict__ Wih1, const float* __restrict__ bih1,
                                                      _Float16* __restrict__ gi, _Float16* __restrict__ g0,
                                                      _Float16* __restrict__ g1, int T, int* __restrict__ flags,
                                                      int NC) {
  int b = blockIdx.x;
  int* done0 = flags + 8;
  int* done1 = flags + 8 + NC;
  if (b == 0)
    gru_scan_dev<0>(Whh0, bhh0, gi, g0, T, flags, done0, NW0);
  else if (b == 1)
    gru_scan_dev<1>(Whh1, bhh1, gi, g1, T, flags, done1, NW1);
  else if (b < 2 + NW0)
    gi0_worker(h2, src, dst, ea, Wih0, bih0, gi, T, b - 2, done0, NC);
  else
    gi1_worker(g0, Wih1, bih1, gi, T, b - 2 - NW0, flags, done1, NC);
}

// ---------------- final MLP: out[t] = Wlin2 . relu(Wlin1 . g1_t + blin1) + blin2 ----------------

__global__ __launch_bounds__(128) void k_final(const _Float16* __restrict__ g1T, const float* __restrict__ Wlin1,
                                               const float* __restrict__ blin1, const float* __restrict__ Wlin2,
                                               const float* __restrict__ blin2, float* __restrict__ out, int E) {
  int j = threadIdx.x;  // 0..127
  float w[256];
#pragma unroll
  for (int k = 0; k < 256; ++k) w[k] = Wlin1[(size_t)j * 256 + k];
  float bj = blin1[j], w2j = Wlin2[j], b2v = blin2[0];
  __shared__ float gsf[256];
  __shared__ float red[128];
  for (int t = blockIdx.x; t < E; t += gridDim.x) {
    gsf[j] = (float)g1T[(size_t)j * E + t];
    gsf[j + 128] = (float)g1T[(size_t)(j + 128) * E + t];
    __syncthreads();
    float acc = 0.f;
#pragma unroll
    for (int k = 0; k < 256; ++k) acc = fmaf(w[k], gsf[k], acc);
    float v = fmaxf(acc + bj, 0.f) * w2j;
    red[j] = v;
    __syncthreads();
    for (int s = 64; s > 0; s >>= 1) {
      if (j < s) red[j] += red[j + s];
      __syncthreads();
    }
    if (j == 0) out[t] = red[0] + b2v;
    __syncthreads();
  }
}

// ---------------- launch ----------------

extern "C" void kernel_launch(void* const* d_in, const int* in_sizes, int n_in,
                              void* d_out, int out_size, void* d_ws, size_t ws_size,
                              hipStream_t stream) {
  (void)n_in; (void)out_size; (void)ws_size;
  const float* x = (const float*)d_in[0];
  const int* ei = (const int*)d_in[1];
  const float* ea = (const float*)d_in[2];
  const float* W1 = (const float*)d_in[3];
  const float* as1 = (const float*)d_in[4];
  const float* ad1 = (const float*)d_in[5];
  const float* b1 = (const float*)d_in[6];
  const float* gamma1 = (const float*)d_in[7];
  const float* beta1 = (const float*)d_in[8];
  const float* mean1 = (const float*)d_in[9];
  const float* var1 = (const float*)d_in[10];
  const float* W2 = (const float*)d_in[11];
  const float* as2 = (const float*)d_in[12];
  const float* ad2 = (const float*)d_in[13];
  const float* b2 = (const float*)d_in[14];
  const float* gamma2 = (const float*)d_in[15];
  const float* beta2 = (const float*)d_in[16];
  const float* mean2 = (const float*)d_in[17];
  const float* var2 = (const float*)d_in[18];
  const float* Wih0 = (const float*)d_in[19];
  const float* Whh0 = (const float*)d_in[20];
  const float* bih0 = (const float*)d_in[21];
  const float* bhh0 = (const float*)d_in[22];
  const float* Wih1 = (const float*)d_in[23];
  const float* Whh1 = (const float*)d_in[24];
  const float* bih1 = (const float*)d_in[25];
  const float* bhh1 = (const float*)d_in[26];
  const float* Wlin1 = (const float*)d_in[27];
  const float* blin1 = (const float*)d_in[28];
  const float* Wlin2 = (const float*)d_in[29];
  const float* blin2 = (const float*)d_in[30];

  int N = in_sizes[0];
  int E = in_sizes[1] / 2;
  const int* src = ei;
  const int* dst = ei + E;

  char* wsp = (char*)d_ws;
  size_t off = 0;
  auto carve = [&](size_t bytes) -> void* {
    void* p = wsp + off;
    off = (off + bytes + 255) & ~(size_t)255;
    return p;
  };
  float* c12 = (float*)carve(2 * sizeof(float));
  float* a1s = (float*)carve((size_t)N * 4);
  float* a1d = (float*)carve((size_t)N * 4);
  unsigned* m1 = (unsigned*)carve((size_t)N * 4);
  float* z1 = (float*)carve((size_t)N * 4);
  float* uacc = (float*)carve((size_t)N * 4);
  float* h1 = (float*)carve((size_t)N * 256 * 4);
  float* xw2 = (float*)carve((size_t)N * 256 * 4);
  float* a2s = (float*)carve((size_t)N * 4);
  float* a2d = (float*)carve((size_t)N * 4);
  unsigned* m2 = (unsigned*)carve((size_t)N * 4);
  float* z2 = (float*)carve((size_t)N * 4);
  float* acc2 = (float*)carve((size_t)N * 256 * 4);          // becomes h2 in-place
  _Float16* gi = (_Float16*)carve((size_t)E * 768 * 2);      // feature-major [768, E]; gi0 then gi1 in place, chunkwise
  _Float16* g0 = (_Float16*)carve((size_t)E * 256 * 2);      // feature-major [256, E]
  _Float16* g1 = (_Float16*)carve((size_t)E * 256 * 2);      // feature-major [256, E]
  int NCh = (E + GCHUNK - 1) / GCHUNK;
  int flagN = 8 + 2 * NCh;                                   // [0]=prog0, done0[NC], done1[NC]
  int* flags = (int*)carve((size_t)flagN * 4);

  hipMemsetAsync(m1, 0, (size_t)N * 4, stream);
  hipMemsetAsync(z1, 0, (size_t)N * 4, stream);
  hipMemsetAsync(uacc, 0, (size_t)N * 4, stream);
  hipMemsetAsync(m2, 0, (size_t)N * 4, stream);
  hipMemsetAsync(z2, 0, (size_t)N * 4, stream);
  hipMemsetAsync(acc2, 0, (size_t)N * 256 * 4, stream);
  hipMemsetAsync(flags, 0, (size_t)flagN * 4, stream);

  int eb = (E + N + 255) / 256;

  k_prep_c<<<1, 256, 0, stream>>>(W1, as1, ad1, c12);
  k_a1<<<(N + 255) / 256, 256, 0, stream>>>(x, c12, a1s, a1d, N);
  k_edge_max<<<eb, 256, 0, stream>>>(a1s, a1d, m1, src, dst, E, N);
  k_gat1_edge_sum<<<eb, 256, 0, stream>>>(a1s, a1d, m1, src, dst, x, z1, uacc, E, N);
  k_gat1_node<<<N, 256, 0, stream>>>(uacc, z1, W1, b1, gamma1, beta1, mean1, var1, h1);

  dim3 gx((N + BM - 1) / BM, 256 / BN);
  k_gemm_f32<<<gx, 256, 0, stream>>>(h1, W2, xw2, N, 256, 256);
  k_rowdots<<<N, 256, 0, stream>>>(xw2, as2, ad2, a2s, a2d);
  k_edge_max<<<eb, 256, 0, stream>>>(a2s, a2d, m2, src, dst, E, N);
  k_gat2_scatter<<<4096, 256, 0, stream>>>(a2s, a2d, m2, src, dst, xw2, z2, acc2, E, N);
  k_gat2_node<<<N, 256, 0, stream>>>(acc2, z2, b2, gamma2, beta2, mean2, var2);

  // fused pipelined GRU: gi0 workers feed scan0; gi1 workers feed scan1.
  k_fused_gru<<<NBLK, 512, 0, stream>>>(Whh0, bhh0, Whh1, bhh1, acc2, src, dst, ea,
                                        Wih0, bih0, Wih1, bih1, gi, g0, g1, E, flags, NCh);

  k_final<<<1024, 128, 0, stream>>>(g1, Wlin1, blin1, Wlin2, blin2, (float*)d_out, E);
}